// Round 4
// baseline (232.021 us; speedup 1.0000x reference)
//
#include <hip/hip_runtime.h>
#include <hip/hip_bf16.h>
#include <stdint.h>

#define BATCH 2
#define NPTS  2048
#define CIN   64
#define COUT  64
#define NCELL 9

// knorm = 315 / (64*pi*0.1^9)  -- folded into dC at prep time
#define KNORM 1.5666851e9f
#define R2 0.01f

typedef __attribute__((ext_vector_type(8))) __bf16 bf16x8;
typedef __attribute__((ext_vector_type(4))) float  f32x4;

union B8 { uint4 u; bf16x8 v; };

static __device__ __forceinline__ unsigned pk2(float a, float b) {
    union { __hip_bfloat162 h; unsigned u; } cv;
    cv.h = __float22bfloat162_rn(make_float2(a, b));
    return cv.u;
}

// ---------------------------------------------------------------------------
// Workspace:
//   posT  float2[B*N]                    32 KB
//   dC    bf16  [B][C][N]  (c-major)    512 KB   -- scaled by KNORM
//   WB    bf16  [9][2ks][4ob][64][8]     72 KB   -- GEMM2 B pre-swizzled frags
// ---------------------------------------------------------------------------

__global__ __launch_bounds__(256) void prep_kernel(
    const float* __restrict__ locs, const float* __restrict__ data,
    const float* __restrict__ density, const float* __restrict__ weight,
    const float* __restrict__ bias,
    float2* __restrict__ posT, uint16_t* __restrict__ dC,
    uint16_t* __restrict__ WB, float* __restrict__ out)
{
    const int tid = threadIdx.x;
    const int g = blockIdx.x;
    if (g < 256) {
        // dC[b][c][j] = bf16( KNORM * data / (invmass * density) )
        int e = g * 256 + tid;             // 4 j each
        int j4 = e & 511, bc = e >> 9;
        int b = bc >> 6;
        float4 dv = *(const float4*)(data + bc * 2048 + j4 * 4);
        float4 de = *(const float4*)(density + b * 2048 + j4 * 4);
        int jb = (b * 2048 + j4 * 4) * 3 + 2;
        float m0 = locs[jb], m1 = locs[jb + 3], m2 = locs[jb + 6], m3 = locs[jb + 9];
        float v0 = dv.x / (m0 * de.x) * KNORM;
        float v1 = dv.y / (m1 * de.y) * KNORM;
        float v2 = dv.z / (m2 * de.z) * KNORM;
        float v3 = dv.w / (m3 * de.w) * KNORM;
        *(uint2*)(dC + bc * 2048 + j4 * 4) = make_uint2(pk2(v0, v1), pk2(v2, v3));
    } else if (g < 272) {
        int jj = (g - 256) * 256 + tid;
        posT[jj] = make_float2(locs[jj * 3], locs[jj * 3 + 1]);
    } else if (g < 272 + NCELL) {
        // WB[cell][ks][ob][lane][jj]: o = ob*16 + (lane&15), c = ks*32 + quad*8 + jj
        int cell = g - 272;
        for (int it = 0; it < 16; it++) {
            int e = it * 256 + tid;
            int ks = e >> 11, ob = (e >> 9) & 3, lane = (e >> 3) & 63, jj = e & 7;
            int o = ob * 16 + (lane & 15);
            int c = ks * 32 + ((lane >> 4) & 3) * 8 + jj;
            union { __hip_bfloat16 h; uint16_t u; } cv;
            cv.h = __float2bfloat16(weight[(o * 64 + c) * 9 + cell]);
            WB[cell * 4096 + e] = cv.u;
        }
    } else {
        // out[b][o][i] = bias[o]  (atomic accumulation target)
        const int gb = g - (272 + NCELL);
#pragma unroll
        for (int r = 0; r < 2; r++) {
            int e4 = (gb * 512 + r * 256 + tid) * 4;
            float bv = bias[(e4 >> 11) & 63];
            *(float4*)(out + e4) = make_float4(bv, bv, bv, bv);
        }
    }
}

// ---------------------------------------------------------------------------
// Fused conv, j-split x8: block = 16-i tile x 256-j range (8 chunks of 32 j).
// Grid 2048 = 8 blocks/CU (32 waves/CU) -- occupancy is the latency-hiding
// lever; round-3 at 4 blocks/CU measured 46us with VALUBusy 35% / HBM 1.4%
// (latency-bound, nothing saturated).
// NO LDS STAGING: dC is L2-resident; each lane's B-frag is a contiguous 16B
// global_load_dwordx4. Main loop has ZERO barriers -- waves free-run.
// Cell->wave assignment is COST-aware (zero offset components):
//   t_k = sv + cx*dx + cy*dy + cc, sv = R2-dx^2-dy^2 shared;
//   rank0:{0,2} rank1:{6,8} rank2:{1,3,4} rank3:{5,7}
// Heavy rank rotated per block (SIMD issue balance). GEMM2 per-wave on its
// own cells via a private LDS transpose slice; block-reduce + fp32 atomics.
// ---------------------------------------------------------------------------
__global__ __launch_bounds__(256, 8) void conv_kernel(
    const float2* __restrict__ posT, const uint16_t* __restrict__ dC,
    const uint16_t* __restrict__ WB, float* __restrict__ out)
{
    __shared__ float sft[4 * 16 * 68];        // per-wave transpose/reduce slices

    const int tid  = threadIdx.x;
    const int lane = tid & 63;
    const int wid  = tid >> 6;
    const int cl   = lane & 15;
    const int quad = lane >> 4;
    const int bx   = blockIdx.x;
    const int b    = bx >> 10;
    const int i0   = ((bx >> 3) & 127) * 16;
    const int jh   = bx & 7;                  // j-range [jh*256, jh*256+256)
    const int jb0  = jh * 256;

    // heavy rank rotated per block (SIMD issue balance across co-resident blocks)
    const int hw = ((bx >> 8) + bx) & 3;
    const int r  = (wid - hw) & 3;

    const float2 pI = posT[b * 2048 + i0 + cl];
    const float2* pbase = posT + b * 2048 + jb0;

    // per-lane base for direct B-frag loads: row c = nb*16+cl, j = jb0+n*32+quad*8
    const uint16_t* dlane = dC + (b * 64 + cl) * 2048 + jb0 + quad * 8;

    f32x4 acc[3][4];
#pragma unroll
    for (int ci = 0; ci < 3; ci++)
#pragma unroll
        for (int nb = 0; nb < 4; nb++) acc[ci][nb] = (f32x4){0.f, 0.f, 0.f, 0.f};

    // per-cell w + 4 MFMA into acc[CI]. CX/CY/CC are literal constants.
#define CELL(CI, CX, CY, CC, HASX, HASY)                                      \
    {                                                                         \
        float w_[8];                                                          \
        _Pragma("unroll")                                                     \
        for (int p = 0; p < 8; p++) {                                         \
            float t = sv[p];                                                  \
            if (HASY) t = fmaf((CY), dyv[p], t);                              \
            if (HASX) t = fmaf((CX), dxv[p], t);                              \
            if ((HASX) || (HASY)) t += (CC);                                  \
            float mt = fmaxf(t, 0.0f);                                        \
            w_[p] = (mt * mt) * mt;                                           \
        }                                                                     \
        B8 af;                                                                \
        af.u = make_uint4(pk2(w_[0], w_[1]), pk2(w_[2], w_[3]),               \
                          pk2(w_[4], w_[5]), pk2(w_[6], w_[7]));              \
        _Pragma("unroll")                                                     \
        for (int nb = 0; nb < 4; nb++)                                        \
            acc[CI][nb] = __builtin_amdgcn_mfma_f32_16x16x32_bf16(            \
                af.v, bf[nb].v, acc[CI][nb], 0, 0, 0);                        \
    }

    for (int n = 0; n < 8; n++) {
        // B-frags direct from global (L1/L2-hot): dcoef[j=quad*8..+7][c=nb*16+cl]
        B8 bf[4];
#pragma unroll
        for (int nb = 0; nb < 4; nb++)
            bf[nb].u = *(const uint4*)(dlane + nb * 16 * 2048 + n * 32);

        // my 8 pair geometries (pj from L1-hot posT)
        const float4* pp = (const float4*)(pbase + n * 32 + quad * 8);
        float4 q0 = pp[0], q1 = pp[1], q2 = pp[2], q3 = pp[3];
        float dxv[8], dyv[8], sv[8];
        dxv[0] = pI.x - q0.x; dyv[0] = pI.y - q0.y;
        dxv[1] = pI.x - q0.z; dyv[1] = pI.y - q0.w;
        dxv[2] = pI.x - q1.x; dyv[2] = pI.y - q1.y;
        dxv[3] = pI.x - q1.z; dyv[3] = pI.y - q1.w;
        dxv[4] = pI.x - q2.x; dyv[4] = pI.y - q2.y;
        dxv[5] = pI.x - q2.z; dyv[5] = pI.y - q2.w;
        dxv[6] = pI.x - q3.x; dyv[6] = pI.y - q3.y;
        dxv[7] = pI.x - q3.z; dyv[7] = pI.y - q3.w;
#pragma unroll
        for (int p = 0; p < 8; p++)
            sv[p] = fmaf(-dyv[p], dyv[p], fmaf(-dxv[p], dxv[p], R2));

        if (r == 0) {            // corners k=0 (ox,oy=-,-), k=2 (-,+)
            CELL(0,  0.1f,  0.1f, -0.005f,  1, 1);
            CELL(1,  0.1f, -0.1f, -0.005f,  1, 1);
        } else if (r == 1) {     // corners k=6 (+,-), k=8 (+,+)
            CELL(0, -0.1f,  0.1f, -0.005f,  1, 1);
            CELL(1, -0.1f, -0.1f, -0.005f,  1, 1);
        } else if (r == 2) {     // edges k=1 (-,0), k=3 (0,-), center k=4
            CELL(0,  0.1f,  0.0f, -0.0025f, 1, 0);
            CELL(1,  0.0f,  0.1f, -0.0025f, 0, 1);
            CELL(2,  0.0f,  0.0f,  0.0f,    0, 0);
        } else {                 // edges k=5 (0,+), k=7 (+,0)
            CELL(0,  0.0f, -0.1f, -0.0025f, 0, 1);
            CELL(1, -0.1f,  0.0f, -0.0025f, 1, 0);
        }
    }

    // cell ids owned by this wave rank (acc index -> absolute cell k)
    const int nc = (r == 2) ? 3 : 2;
    int kcs[3];
    if (r == 0)      { kcs[0] = 0; kcs[1] = 2; kcs[2] = 0; }
    else if (r == 1) { kcs[0] = 6; kcs[1] = 8; kcs[2] = 0; }
    else if (r == 2) { kcs[0] = 1; kcs[1] = 3; kcs[2] = 4; }
    else             { kcs[0] = 5; kcs[1] = 7; kcs[2] = 0; }

    // ---- GEMM2 per wave: out16x64 partial = sum_{own cells} field_k . W_k --
    float* scr = &sft[wid * (16 * 68)];
    f32x4 acc2[4];
#pragma unroll
    for (int ob = 0; ob < 4; ob++) acc2[ob] = (f32x4){0.f, 0.f, 0.f, 0.f};

#pragma unroll
    for (int ci = 0; ci < 3; ci++) {
        if (ci < nc) {
            // C-frag (row=i=quad*4+rr, col=c=nb*16+cl) -> scr[i][c]
#pragma unroll
            for (int nb = 0; nb < 4; nb++)
#pragma unroll
                for (int rr = 0; rr < 4; rr++)
                    scr[(quad * 4 + rr) * 68 + nb * 16 + cl] = acc[ci][nb][rr];
            // A-frags (m=i=cl, k=c=quad*8+jj) + WB B-frags
            int k = kcs[ci];
#pragma unroll
            for (int ks = 0; ks < 2; ks++) {
                const float* fp = &scr[cl * 68 + ks * 32 + quad * 8];
                float4 lo = *(const float4*)fp;
                float4 hi = *(const float4*)(fp + 4);
                B8 af;
                af.u = make_uint4(pk2(lo.x, lo.y), pk2(lo.z, lo.w),
                                  pk2(hi.x, hi.y), pk2(hi.z, hi.w));
#pragma unroll
                for (int ob = 0; ob < 4; ob++) {
                    B8 wf;
                    wf.u = *(const uint4*)(WB + k * 4096 + (ks * 4 + ob) * 512 + lane * 8);
                    acc2[ob] = __builtin_amdgcn_mfma_f32_16x16x32_bf16(
                        af.v, wf.v, acc2[ob], 0, 0, 0);
                }
            }
        }
    }

    // acc2 C-frag (row=i=quad*4+rr, col=o'=cl; o=ob*16+cl) -> scr[i][o]
    // (scr slice is wave-private; only the cross-wave reduce needs a barrier)
#pragma unroll
    for (int ob = 0; ob < 4; ob++)
#pragma unroll
        for (int rr = 0; rr < 4; rr++)
            scr[(quad * 4 + rr) * 68 + ob * 16 + cl] = acc2[ob][rr];
    __syncthreads();

    // reduce 4 wave-slices, atomically add to out. thread = (og, i)
    {
        const int i  = tid & 15;
        const int og = tid >> 4;              // 16 groups of 4 o
        float4 s0 = *(const float4*)&sft[0 * 1088 + i * 68 + og * 4];
        float4 s1 = *(const float4*)&sft[1 * 1088 + i * 68 + og * 4];
        float4 s2 = *(const float4*)&sft[2 * 1088 + i * 68 + og * 4];
        float4 s3 = *(const float4*)&sft[3 * 1088 + i * 68 + og * 4];
        float v0 = s0.x + s1.x + s2.x + s3.x;
        float v1 = s0.y + s1.y + s2.y + s3.y;
        float v2 = s0.z + s1.z + s2.z + s3.z;
        float v3 = s0.w + s1.w + s2.w + s3.w;
        float* ob_ = out + (b * 64 + og * 4) * 2048 + i0 + i;
        unsafeAtomicAdd(ob_ + 0 * 2048, v0);
        unsafeAtomicAdd(ob_ + 1 * 2048, v1);
        unsafeAtomicAdd(ob_ + 2 * 2048, v2);
        unsafeAtomicAdd(ob_ + 3 * 2048, v3);
    }
#undef CELL
}

extern "C" void kernel_launch(void* const* d_in, const int* in_sizes, int n_in,
                              void* d_out, int out_size, void* d_ws, size_t ws_size,
                              hipStream_t stream)
{
    const float* locs    = (const float*)d_in[0];   // (B, N, 3)
    const float* data    = (const float*)d_in[1];   // (B, CIN, N)
    const float* density = (const float*)d_in[2];   // (B, N)
    const float* weight  = (const float*)d_in[3];   // (COUT, CIN, 9)
    const float* bias    = (const float*)d_in[4];   // (COUT,)
    float* out = (float*)d_out;                     // (B, COUT, N)

    float2*   posT = (float2*)d_ws;                             // 32768 B
    uint16_t* dC   = (uint16_t*)((char*)d_ws + 32768);          // 524288 B
    uint16_t* WB   = (uint16_t*)((char*)d_ws + 32768 + 524288); // 73728 B

    prep_kernel<<<272 + NCELL + 128, 256, 0, stream>>>(
        locs, data, density, weight, bias, posT, dC, WB, out);
    conv_kernel<<<BATCH * 128 * 8, 256, 0, stream>>>(posT, dC, WB, out);
}

// Round 5
// 121.447 us; speedup vs baseline: 1.9105x; 1.9105x over previous
//
#include <hip/hip_runtime.h>
#include <hip/hip_bf16.h>
#include <stdint.h>

#define BATCH 2
#define NPTS  2048
#define CIN   64
#define COUT  64
#define NCELL 9

// knorm = 315 / (64*pi*0.1^9)  -- folded into dC at prep time
#define KNORM 1.5666851e9f
#define R2 0.01f

typedef __attribute__((ext_vector_type(8))) __bf16 bf16x8;
typedef __attribute__((ext_vector_type(4))) float  f32x4;

union B8 { uint4 u; bf16x8 v; };

static __device__ __forceinline__ unsigned pk2(float a, float b) {
    union { __hip_bfloat162 h; unsigned u; } cv;
    cv.h = __float22bfloat162_rn(make_float2(a, b));
    return cv.u;
}

// ---------------------------------------------------------------------------
// Workspace:
//   posT  float2[B*N]                    32 KB
//   dC    bf16  [B][C][N]  (c-major)    512 KB   -- scaled by KNORM
//   WB    bf16  [9][2ks][4ob][64][8]     72 KB   -- GEMM2 B pre-swizzled frags
// ---------------------------------------------------------------------------

__global__ __launch_bounds__(256) void prep_kernel(
    const float* __restrict__ locs, const float* __restrict__ data,
    const float* __restrict__ density, const float* __restrict__ weight,
    const float* __restrict__ bias,
    float2* __restrict__ posT, uint16_t* __restrict__ dC,
    uint16_t* __restrict__ WB, float* __restrict__ out)
{
    const int tid = threadIdx.x;
    const int g = blockIdx.x;
    if (g < 256) {
        // dC[b][c][j] = bf16( KNORM * data / (invmass * density) )
        int e = g * 256 + tid;             // 4 j each
        int j4 = e & 511, bc = e >> 9;
        int b = bc >> 6;
        float4 dv = *(const float4*)(data + bc * 2048 + j4 * 4);
        float4 de = *(const float4*)(density + b * 2048 + j4 * 4);
        int jb = (b * 2048 + j4 * 4) * 3 + 2;
        float m0 = locs[jb], m1 = locs[jb + 3], m2 = locs[jb + 6], m3 = locs[jb + 9];
        float v0 = dv.x / (m0 * de.x) * KNORM;
        float v1 = dv.y / (m1 * de.y) * KNORM;
        float v2 = dv.z / (m2 * de.z) * KNORM;
        float v3 = dv.w / (m3 * de.w) * KNORM;
        *(uint2*)(dC + bc * 2048 + j4 * 4) = make_uint2(pk2(v0, v1), pk2(v2, v3));
    } else if (g < 272) {
        int jj = (g - 256) * 256 + tid;
        posT[jj] = make_float2(locs[jj * 3], locs[jj * 3 + 1]);
    } else if (g < 272 + NCELL) {
        // WB[cell][ks][ob][lane][jj]: o = ob*16 + (lane&15), c = ks*32 + quad*8 + jj
        int cell = g - 272;
        for (int it = 0; it < 16; it++) {
            int e = it * 256 + tid;
            int ks = e >> 11, ob = (e >> 9) & 3, lane = (e >> 3) & 63, jj = e & 7;
            int o = ob * 16 + (lane & 15);
            int c = ks * 32 + ((lane >> 4) & 3) * 8 + jj;
            union { __hip_bfloat16 h; uint16_t u; } cv;
            cv.h = __float2bfloat16(weight[(o * 64 + c) * 9 + cell]);
            WB[cell * 4096 + e] = cv.u;
        }
    } else {
        // out[b][o][i] = bias[o]  (atomic accumulation target)
        const int gb = g - (272 + NCELL);
#pragma unroll
        for (int r = 0; r < 2; r++) {
            int e4 = (gb * 512 + r * 256 + tid) * 4;
            float bv = bias[(e4 >> 11) & 63];
            *(float4*)(out + e4) = make_float4(bv, bv, bv, bv);
        }
    }
}

// ---------------------------------------------------------------------------
// Fused conv, j-split x4: block = 16-i tile x 512-j range (16 chunks of 32 j).
// NO LDS STAGING, NO MAIN-LOOP BARRIERS: dC is L2-resident; B-frags are
// direct 16B global loads, REGISTER-DOUBLE-BUFFERED one chunk ahead
// (manual 2x unroll, named bufA/bufB -- use-distance ~1 compute block covers
// L2 latency; this was the r1->r3 regression cause at only 4 waves/SIMD).
// Register budget: 56 VGPR + 16 prefetch + 48 AGPR acc = ~120 <= 128 cap
// (bound 4). NEVER cap below that: r4's bound-8 spilled 460MB to scratch.
// Cell->wave split cost-aware: rank0:{0,2} r1:{6,8} r2:{1,3,4} r3:{5,7},
// heavy rank rotated per block. GEMM2 per-wave via private LDS transpose
// slice; block-reduce + fp32 atomics into out.
// ---------------------------------------------------------------------------
__global__ __launch_bounds__(256, 4) void conv_kernel(
    const float2* __restrict__ posT, const uint16_t* __restrict__ dC,
    const uint16_t* __restrict__ WB, float* __restrict__ out)
{
    __shared__ float sft[4 * 16 * 68];        // per-wave transpose/reduce slices

    const int tid  = threadIdx.x;
    const int lane = tid & 63;
    const int wid  = tid >> 6;
    const int cl   = lane & 15;
    const int quad = lane >> 4;
    const int bx   = blockIdx.x;
    const int b    = bx >> 9;
    const int i0   = ((bx >> 2) & 127) * 16;
    const int jh   = bx & 3;                  // j-range [jh*512, jh*512+512)
    const int jb0  = jh * 512;

    // heavy rank rotated per block (SIMD issue balance across co-resident blocks)
    const int hw = ((bx >> 8) + bx) & 3;
    const int r  = (wid - hw) & 3;

    const float2 pI = posT[b * 2048 + i0 + cl];
    const float2* pbase = posT + b * 2048 + jb0;

    // per-lane base for direct B-frag loads: row c = nb*16+cl, j = jb0+n*32+quad*8
    const uint16_t* dlane = dC + (b * 64 + cl) * 2048 + jb0 + quad * 8;

    f32x4 acc[3][4];
#pragma unroll
    for (int ci = 0; ci < 3; ci++)
#pragma unroll
        for (int nb = 0; nb < 4; nb++) acc[ci][nb] = (f32x4){0.f, 0.f, 0.f, 0.f};

    // per-cell w + 4 MFMA into acc[CI]. CX/CY/CC are literal constants.
#define CELL(BF, CI, CX, CY, CC, HASX, HASY)                                  \
    {                                                                         \
        float w_[8];                                                          \
        _Pragma("unroll")                                                     \
        for (int p = 0; p < 8; p++) {                                         \
            float t = sv[p];                                                  \
            if (HASY) t = fmaf((CY), dyv[p], t);                              \
            if (HASX) t = fmaf((CX), dxv[p], t);                              \
            if ((HASX) || (HASY)) t += (CC);                                  \
            float mt = fmaxf(t, 0.0f);                                        \
            w_[p] = (mt * mt) * mt;                                           \
        }                                                                     \
        B8 af;                                                                \
        af.u = make_uint4(pk2(w_[0], w_[1]), pk2(w_[2], w_[3]),               \
                          pk2(w_[4], w_[5]), pk2(w_[6], w_[7]));              \
        _Pragma("unroll")                                                     \
        for (int nb = 0; nb < 4; nb++)                                        \
            acc[CI][nb] = __builtin_amdgcn_mfma_f32_16x16x32_bf16(            \
                af.v, BF[nb].v, acc[CI][nb], 0, 0, 0);                        \
    }

    // full per-chunk compute using B-frags already resident in registers
#define COMPUTE(N, BF)                                                        \
    {                                                                         \
        const float4* pp = (const float4*)(pbase + (N) * 32 + quad * 8);      \
        float4 q0 = pp[0], q1 = pp[1], q2 = pp[2], q3 = pp[3];                \
        float dxv[8], dyv[8], sv[8];                                          \
        dxv[0] = pI.x - q0.x; dyv[0] = pI.y - q0.y;                           \
        dxv[1] = pI.x - q0.z; dyv[1] = pI.y - q0.w;                           \
        dxv[2] = pI.x - q1.x; dyv[2] = pI.y - q1.y;                           \
        dxv[3] = pI.x - q1.z; dyv[3] = pI.y - q1.w;                           \
        dxv[4] = pI.x - q2.x; dyv[4] = pI.y - q2.y;                           \
        dxv[5] = pI.x - q2.z; dyv[5] = pI.y - q2.w;                           \
        dxv[6] = pI.x - q3.x; dyv[6] = pI.y - q3.y;                           \
        dxv[7] = pI.x - q3.z; dyv[7] = pI.y - q3.w;                           \
        _Pragma("unroll")                                                     \
        for (int p = 0; p < 8; p++)                                           \
            sv[p] = fmaf(-dyv[p], dyv[p], fmaf(-dxv[p], dxv[p], R2));         \
        if (r == 0) {            /* corners k=0 (-,-), k=2 (-,+) */           \
            CELL(BF, 0,  0.1f,  0.1f, -0.005f,  1, 1);                        \
            CELL(BF, 1,  0.1f, -0.1f, -0.005f,  1, 1);                        \
        } else if (r == 1) {     /* corners k=6 (+,-), k=8 (+,+) */           \
            CELL(BF, 0, -0.1f,  0.1f, -0.005f,  1, 1);                        \
            CELL(BF, 1, -0.1f, -0.1f, -0.005f,  1, 1);                        \
        } else if (r == 2) {     /* edges k=1, k=3, center k=4 */             \
            CELL(BF, 0,  0.1f,  0.0f, -0.0025f, 1, 0);                        \
            CELL(BF, 1,  0.0f,  0.1f, -0.0025f, 0, 1);                        \
            CELL(BF, 2,  0.0f,  0.0f,  0.0f,    0, 0);                        \
        } else {                 /* edges k=5, k=7 */                         \
            CELL(BF, 0,  0.0f, -0.1f, -0.0025f, 0, 1);                        \
            CELL(BF, 1, -0.1f,  0.0f, -0.0025f, 1, 0);                        \
        }                                                                     \
    }

#define LOADBF(DST, N)                                                        \
    _Pragma("unroll")                                                         \
    for (int nb = 0; nb < 4; nb++)                                            \
        DST[nb].u = *(const uint4*)(dlane + nb * 16 * 2048 + (N) * 32);

    B8 bA[4], bB[4];
    LOADBF(bA, 0);

    for (int n = 0; n < 16; n += 2) {
        LOADBF(bB, n + 1);                    // prefetch: in flight over COMPUTE(n)
        COMPUTE(n, bA);
        if (n + 2 < 16) LOADBF(bA, n + 2);    // prefetch over COMPUTE(n+1)
        COMPUTE(n + 1, bB);
    }

    // cell ids owned by this wave rank (acc index -> absolute cell k)
    const int nc = (r == 2) ? 3 : 2;
    int kcs[3];
    if (r == 0)      { kcs[0] = 0; kcs[1] = 2; kcs[2] = 0; }
    else if (r == 1) { kcs[0] = 6; kcs[1] = 8; kcs[2] = 0; }
    else if (r == 2) { kcs[0] = 1; kcs[1] = 3; kcs[2] = 4; }
    else             { kcs[0] = 5; kcs[1] = 7; kcs[2] = 0; }

    // ---- GEMM2 per wave: out16x64 partial = sum_{own cells} field_k . W_k --
    float* scr = &sft[wid * (16 * 68)];
    f32x4 acc2[4];
#pragma unroll
    for (int ob = 0; ob < 4; ob++) acc2[ob] = (f32x4){0.f, 0.f, 0.f, 0.f};

#pragma unroll
    for (int ci = 0; ci < 3; ci++) {
        if (ci < nc) {
            // C-frag (row=i=quad*4+rr, col=c=nb*16+cl) -> scr[i][c]
#pragma unroll
            for (int nb = 0; nb < 4; nb++)
#pragma unroll
                for (int rr = 0; rr < 4; rr++)
                    scr[(quad * 4 + rr) * 68 + nb * 16 + cl] = acc[ci][nb][rr];
            // A-frags (m=i=cl, k=c=quad*8+jj) + WB B-frags
            int k = kcs[ci];
#pragma unroll
            for (int ks = 0; ks < 2; ks++) {
                const float* fp = &scr[cl * 68 + ks * 32 + quad * 8];
                float4 lo = *(const float4*)fp;
                float4 hi = *(const float4*)(fp + 4);
                B8 af;
                af.u = make_uint4(pk2(lo.x, lo.y), pk2(lo.z, lo.w),
                                  pk2(hi.x, hi.y), pk2(hi.z, hi.w));
#pragma unroll
                for (int ob = 0; ob < 4; ob++) {
                    B8 wf;
                    wf.u = *(const uint4*)(WB + k * 4096 + (ks * 4 + ob) * 512 + lane * 8);
                    acc2[ob] = __builtin_amdgcn_mfma_f32_16x16x32_bf16(
                        af.v, wf.v, acc2[ob], 0, 0, 0);
                }
            }
        }
    }

    // acc2 C-frag (row=i=quad*4+rr, col=o'=cl; o=ob*16+cl) -> scr[i][o]
    // (scr slice is wave-private; only the cross-wave reduce needs a barrier)
#pragma unroll
    for (int ob = 0; ob < 4; ob++)
#pragma unroll
        for (int rr = 0; rr < 4; rr++)
            scr[(quad * 4 + rr) * 68 + ob * 16 + cl] = acc2[ob][rr];
    __syncthreads();

    // reduce 4 wave-slices, atomically add to out. thread = (og, i)
    {
        const int i  = tid & 15;
        const int og = tid >> 4;              // 16 groups of 4 o
        float4 s0 = *(const float4*)&sft[0 * 1088 + i * 68 + og * 4];
        float4 s1 = *(const float4*)&sft[1 * 1088 + i * 68 + og * 4];
        float4 s2 = *(const float4*)&sft[2 * 1088 + i * 68 + og * 4];
        float4 s3 = *(const float4*)&sft[3 * 1088 + i * 68 + og * 4];
        float v0 = s0.x + s1.x + s2.x + s3.x;
        float v1 = s0.y + s1.y + s2.y + s3.y;
        float v2 = s0.z + s1.z + s2.z + s3.z;
        float v3 = s0.w + s1.w + s2.w + s3.w;
        float* ob_ = out + (b * 64 + og * 4) * 2048 + i0 + i;
        unsafeAtomicAdd(ob_ + 0 * 2048, v0);
        unsafeAtomicAdd(ob_ + 1 * 2048, v1);
        unsafeAtomicAdd(ob_ + 2 * 2048, v2);
        unsafeAtomicAdd(ob_ + 3 * 2048, v3);
    }
#undef CELL
#undef COMPUTE
#undef LOADBF
}

extern "C" void kernel_launch(void* const* d_in, const int* in_sizes, int n_in,
                              void* d_out, int out_size, void* d_ws, size_t ws_size,
                              hipStream_t stream)
{
    const float* locs    = (const float*)d_in[0];   // (B, N, 3)
    const float* data    = (const float*)d_in[1];   // (B, CIN, N)
    const float* density = (const float*)d_in[2];   // (B, N)
    const float* weight  = (const float*)d_in[3];   // (COUT, CIN, 9)
    const float* bias    = (const float*)d_in[4];   // (COUT,)
    float* out = (float*)d_out;                     // (B, COUT, N)

    float2*   posT = (float2*)d_ws;                             // 32768 B
    uint16_t* dC   = (uint16_t*)((char*)d_ws + 32768);          // 524288 B
    uint16_t* WB   = (uint16_t*)((char*)d_ws + 32768 + 524288); // 73728 B

    prep_kernel<<<272 + NCELL + 128, 256, 0, stream>>>(
        locs, data, density, weight, bias, posT, dC, WB, out);
    conv_kernel<<<BATCH * 128 * 4, 256, 0, stream>>>(posT, dC, WB, out);
}

// Round 6
// 88.959 us; speedup vs baseline: 2.6082x; 1.3652x over previous
//
#include <hip/hip_runtime.h>
#include <hip/hip_bf16.h>
#include <stdint.h>

#define BATCH 2
#define NPTS  2048
#define CIN   64
#define COUT  64
#define NCELL 9

// knorm = 315 / (64*pi*0.1^9)  -- folded into dC at prep time
#define KNORM 1.5666851e9f
#define R2 0.01f

typedef __attribute__((ext_vector_type(8))) __bf16 bf16x8;
typedef __attribute__((ext_vector_type(4))) float  f32x4;

union B8 { uint4 u; bf16x8 v; };

typedef __attribute__((address_space(3))) uint8_t        lds_t;
typedef const __attribute__((address_space(1))) uint8_t  glb_t;

static __device__ __forceinline__ unsigned pk2(float a, float b) {
    union { __hip_bfloat162 h; unsigned u; } cv;
    cv.h = __float22bfloat162_rn(make_float2(a, b));
    return cv.u;
}

// ---------------------------------------------------------------------------
// Workspace:
//   posT  float2[B*N]                    32 KB
//   dC    bf16  [B][C][N]  (c-major)    512 KB   -- scaled by KNORM
//   WB    bf16  [9][2ks][4ob][64][8]     72 KB   -- GEMM2 B pre-swizzled frags
// ---------------------------------------------------------------------------

__global__ __launch_bounds__(256) void prep_kernel(
    const float* __restrict__ locs, const float* __restrict__ data,
    const float* __restrict__ density, const float* __restrict__ weight,
    const float* __restrict__ bias,
    float2* __restrict__ posT, uint16_t* __restrict__ dC,
    uint16_t* __restrict__ WB, float* __restrict__ out)
{
    const int tid = threadIdx.x;
    const int g = blockIdx.x;
    if (g < 256) {
        // dC[b][c][j] = bf16( KNORM * data / (invmass * density) )
        int e = g * 256 + tid;             // 4 j each
        int j4 = e & 511, bc = e >> 9;
        int b = bc >> 6;
        float4 dv = *(const float4*)(data + bc * 2048 + j4 * 4);
        float4 de = *(const float4*)(density + b * 2048 + j4 * 4);
        int jb = (b * 2048 + j4 * 4) * 3 + 2;
        float m0 = locs[jb], m1 = locs[jb + 3], m2 = locs[jb + 6], m3 = locs[jb + 9];
        float v0 = dv.x / (m0 * de.x) * KNORM;
        float v1 = dv.y / (m1 * de.y) * KNORM;
        float v2 = dv.z / (m2 * de.z) * KNORM;
        float v3 = dv.w / (m3 * de.w) * KNORM;
        *(uint2*)(dC + bc * 2048 + j4 * 4) = make_uint2(pk2(v0, v1), pk2(v2, v3));
    } else if (g < 272) {
        int jj = (g - 256) * 256 + tid;
        posT[jj] = make_float2(locs[jj * 3], locs[jj * 3 + 1]);
    } else if (g < 272 + NCELL) {
        // WB[cell][ks][ob][lane][jj]: o = ob*16 + (lane&15), c = ks*32 + quad*8 + jj
        int cell = g - 272;
        for (int it = 0; it < 16; it++) {
            int e = it * 256 + tid;
            int ks = e >> 11, ob = (e >> 9) & 3, lane = (e >> 3) & 63, jj = e & 7;
            int o = ob * 16 + (lane & 15);
            int c = ks * 32 + ((lane >> 4) & 3) * 8 + jj;
            union { __hip_bfloat16 h; uint16_t u; } cv;
            cv.h = __float2bfloat16(weight[(o * 64 + c) * 9 + cell]);
            WB[cell * 4096 + e] = cv.u;
        }
    } else {
        // out[b][o][i] = bias[o]  (atomic accumulation target)
        const int gb = g - (272 + NCELL);
#pragma unroll
        for (int r = 0; r < 2; r++) {
            int e4 = (gb * 512 + r * 256 + tid) * 4;
            float bv = bias[(e4 >> 11) & 63];
            *(float4*)(out + e4) = make_float4(bv, bv, bv, bv);
        }
    }
}

// ---------------------------------------------------------------------------
// Fused conv, j-split x4: block = 16-i tile x 512-j range (16 chunks of 32 j).
// STRUCTURE = round-1 measured optimum (conv ~33us): single-chunk LDS
// staging via global_load_lds (no VGPR cost), ONE barrier per chunk, the
// vmcnt(0) drain at the barrier mostly covered by the ~450cy compute block.
//   [ledger: r1 staged 33 < r2 paired 44 < r3 direct-global 46 < r5 reg-dbuf
//    65 (vmcnt in-order defeats prefetch + spill) < r4 bound-8 spills 175.
//    Occupancy capped at 4 waves/SIMD by 56 VGPR + 48 AGPR acc; do NOT
//    raise launch_bounds.]
// CELLS = cost-aware split (zero offset components kill fmas):
//   t_k = sv + cx*dx + cy*dy + cc, sv = R2-dx^2-dy^2 shared;
//   rank0:{0,2} rank1:{6,8} rank2:{1,3,4} rank3:{5,7}; heavy rank rotated
//   per block (SIMD issue balance). GEMM2 per-wave on own cells via private
//   LDS transpose slice; block-reduce + fp32 atomics into out.
// ---------------------------------------------------------------------------
__global__ __launch_bounds__(256, 4) void conv_kernel(
    const float2* __restrict__ posT, const uint16_t* __restrict__ dC,
    const uint16_t* __restrict__ WB, float* __restrict__ out)
{
    __shared__ uint16_t db[2][2048];          // 2 x 4KB: [c][32j] bf16, unpadded
    __shared__ float    sft[4 * 16 * 68];     // per-wave transpose/reduce slices

    const int tid  = threadIdx.x;
    const int lane = tid & 63;
    const int wid  = tid >> 6;
    const int cl   = lane & 15;
    const int quad = lane >> 4;
    const int bx   = blockIdx.x;
    const int b    = bx >> 9;
    const int i0   = ((bx >> 2) & 127) * 16;
    const int jh   = bx & 3;                  // j-range [jh*512, jh*512+512)
    const int jb0  = jh * 512;

    // heavy rank rotated per block (SIMD issue balance across co-resident blocks)
    const int hw = ((bx >> 8) + bx) & 3;
    const int r  = (wid - hw) & 3;

    const float2 pI = posT[b * 2048 + i0 + cl];
    const float2* pbase = posT + b * 2048 + jb0;

    f32x4 acc[3][4];
#pragma unroll
    for (int ci = 0; ci < 3; ci++)
#pragma unroll
        for (int nb = 0; nb < 4; nb++) acc[ci][nb] = (f32x4){0.f, 0.f, 0.f, 0.f};

    // staging: one global_load_lds(16B) per thread per chunk
    const uint16_t* srcbase =
        dC + (b * 64 + wid * 16 + (lane >> 2)) * 2048 + jb0 + (lane & 3) * 8;

#define STAGE(n, buf)                                                         \
    __builtin_amdgcn_global_load_lds((glb_t*)(srcbase + (n) * 32),            \
                                     (lds_t*)(&db[buf][wid * 512]), 16, 0, 0)

    // per-cell w + 4 MFMA into acc[CI]. CX/CY/CC are literal constants.
#define CELL(CI, CX, CY, CC, HASX, HASY)                                      \
    {                                                                         \
        float w_[8];                                                          \
        _Pragma("unroll")                                                     \
        for (int p = 0; p < 8; p++) {                                         \
            float t = sv[p];                                                  \
            if (HASY) t = fmaf((CY), dyv[p], t);                              \
            if (HASX) t = fmaf((CX), dxv[p], t);                              \
            if ((HASX) || (HASY)) t += (CC);                                  \
            float mt = fmaxf(t, 0.0f);                                        \
            w_[p] = (mt * mt) * mt;                                           \
        }                                                                     \
        B8 af;                                                                \
        af.u = make_uint4(pk2(w_[0], w_[1]), pk2(w_[2], w_[3]),               \
                          pk2(w_[4], w_[5]), pk2(w_[6], w_[7]));              \
        _Pragma("unroll")                                                     \
        for (int nb = 0; nb < 4; nb++)                                        \
            acc[CI][nb] = __builtin_amdgcn_mfma_f32_16x16x32_bf16(            \
                af.v, bf[nb].v, acc[CI][nb], 0, 0, 0);                        \
    }

    STAGE(0, 0);

    for (int n = 0; n < 16; n++) {
        __syncthreads();                      // chunk n staged (vmcnt drained)
        if (n < 15) STAGE(n + 1, (n + 1) & 1);
        const int buf = n & 1;

        // B-frags: dcoef[j=quad*8..+7][c=nb*16+cl]
        B8 bf[4];
#pragma unroll
        for (int nb = 0; nb < 4; nb++)
            bf[nb].u = *(const uint4*)&db[buf][(nb * 16 + cl) * 32 + quad * 8];

        // my 8 pair geometries (pj from L1-hot posT)
        const float4* pp = (const float4*)(pbase + n * 32 + quad * 8);
        float4 q0 = pp[0], q1 = pp[1], q2 = pp[2], q3 = pp[3];
        float dxv[8], dyv[8], sv[8];
        dxv[0] = pI.x - q0.x; dyv[0] = pI.y - q0.y;
        dxv[1] = pI.x - q0.z; dyv[1] = pI.y - q0.w;
        dxv[2] = pI.x - q1.x; dyv[2] = pI.y - q1.y;
        dxv[3] = pI.x - q1.z; dyv[3] = pI.y - q1.w;
        dxv[4] = pI.x - q2.x; dyv[4] = pI.y - q2.y;
        dxv[5] = pI.x - q2.z; dyv[5] = pI.y - q2.w;
        dxv[6] = pI.x - q3.x; dyv[6] = pI.y - q3.y;
        dxv[7] = pI.x - q3.z; dyv[7] = pI.y - q3.w;
#pragma unroll
        for (int p = 0; p < 8; p++)
            sv[p] = fmaf(-dyv[p], dyv[p], fmaf(-dxv[p], dxv[p], R2));

        if (r == 0) {            // corners k=0 (ox,oy=-,-), k=2 (-,+)
            CELL(0,  0.1f,  0.1f, -0.005f,  1, 1);
            CELL(1,  0.1f, -0.1f, -0.005f,  1, 1);
        } else if (r == 1) {     // corners k=6 (+,-), k=8 (+,+)
            CELL(0, -0.1f,  0.1f, -0.005f,  1, 1);
            CELL(1, -0.1f, -0.1f, -0.005f,  1, 1);
        } else if (r == 2) {     // edges k=1 (-,0), k=3 (0,-), center k=4
            CELL(0,  0.1f,  0.0f, -0.0025f, 1, 0);
            CELL(1,  0.0f,  0.1f, -0.0025f, 0, 1);
            CELL(2,  0.0f,  0.0f,  0.0f,    0, 0);
        } else {                 // edges k=5 (0,+), k=7 (+,0)
            CELL(0,  0.0f, -0.1f, -0.0025f, 0, 1);
            CELL(1, -0.1f,  0.0f, -0.0025f, 1, 0);
        }
    }

    // cell ids owned by this wave rank (acc index -> absolute cell k)
    const int nc = (r == 2) ? 3 : 2;
    int kcs[3];
    if (r == 0)      { kcs[0] = 0; kcs[1] = 2; kcs[2] = 0; }
    else if (r == 1) { kcs[0] = 6; kcs[1] = 8; kcs[2] = 0; }
    else if (r == 2) { kcs[0] = 1; kcs[1] = 3; kcs[2] = 4; }
    else             { kcs[0] = 5; kcs[1] = 7; kcs[2] = 0; }

    // ---- GEMM2 per wave: out16x64 partial = sum_{own cells} field_k . W_k --
    float* scr = &sft[wid * (16 * 68)];
    f32x4 acc2[4];
#pragma unroll
    for (int ob = 0; ob < 4; ob++) acc2[ob] = (f32x4){0.f, 0.f, 0.f, 0.f};

#pragma unroll
    for (int ci = 0; ci < 3; ci++) {
        if (ci < nc) {
            // C-frag (row=i=quad*4+rr, col=c=nb*16+cl) -> scr[i][c]
#pragma unroll
            for (int nb = 0; nb < 4; nb++)
#pragma unroll
                for (int rr = 0; rr < 4; rr++)
                    scr[(quad * 4 + rr) * 68 + nb * 16 + cl] = acc[ci][nb][rr];
            // A-frags (m=i=cl, k=c=quad*8+jj) + WB B-frags
            int k = kcs[ci];
#pragma unroll
            for (int ks = 0; ks < 2; ks++) {
                const float* fp = &scr[cl * 68 + ks * 32 + quad * 8];
                float4 lo = *(const float4*)fp;
                float4 hi = *(const float4*)(fp + 4);
                B8 af;
                af.u = make_uint4(pk2(lo.x, lo.y), pk2(lo.z, lo.w),
                                  pk2(hi.x, hi.y), pk2(hi.z, hi.w));
#pragma unroll
                for (int ob = 0; ob < 4; ob++) {
                    B8 wf;
                    wf.u = *(const uint4*)(WB + k * 4096 + (ks * 4 + ob) * 512 + lane * 8);
                    acc2[ob] = __builtin_amdgcn_mfma_f32_16x16x32_bf16(
                        af.v, wf.v, acc2[ob], 0, 0, 0);
                }
            }
        }
    }

    // acc2 C-frag (row=i=quad*4+rr, col=o'=cl; o=ob*16+cl) -> scr[i][o]
    // (scr slice is wave-private; only the cross-wave reduce needs a barrier)
#pragma unroll
    for (int ob = 0; ob < 4; ob++)
#pragma unroll
        for (int rr = 0; rr < 4; rr++)
            scr[(quad * 4 + rr) * 68 + ob * 16 + cl] = acc2[ob][rr];
    __syncthreads();

    // reduce 4 wave-slices, atomically add to out. thread = (og, i)
    {
        const int i  = tid & 15;
        const int og = tid >> 4;              // 16 groups of 4 o
        float4 s0 = *(const float4*)&sft[0 * 1088 + i * 68 + og * 4];
        float4 s1 = *(const float4*)&sft[1 * 1088 + i * 68 + og * 4];
        float4 s2 = *(const float4*)&sft[2 * 1088 + i * 68 + og * 4];
        float4 s3 = *(const float4*)&sft[3 * 1088 + i * 68 + og * 4];
        float v0 = s0.x + s1.x + s2.x + s3.x;
        float v1 = s0.y + s1.y + s2.y + s3.y;
        float v2 = s0.z + s1.z + s2.z + s3.z;
        float v3 = s0.w + s1.w + s2.w + s3.w;
        float* ob_ = out + (b * 64 + og * 4) * 2048 + i0 + i;
        unsafeAtomicAdd(ob_ + 0 * 2048, v0);
        unsafeAtomicAdd(ob_ + 1 * 2048, v1);
        unsafeAtomicAdd(ob_ + 2 * 2048, v2);
        unsafeAtomicAdd(ob_ + 3 * 2048, v3);
    }
#undef STAGE
#undef CELL
}

extern "C" void kernel_launch(void* const* d_in, const int* in_sizes, int n_in,
                              void* d_out, int out_size, void* d_ws, size_t ws_size,
                              hipStream_t stream)
{
    const float* locs    = (const float*)d_in[0];   // (B, N, 3)
    const float* data    = (const float*)d_in[1];   // (B, CIN, N)
    const float* density = (const float*)d_in[2];   // (B, N)
    const float* weight  = (const float*)d_in[3];   // (COUT, CIN, 9)
    const float* bias    = (const float*)d_in[4];   // (COUT,)
    float* out = (float*)d_out;                     // (B, COUT, N)

    float2*   posT = (float2*)d_ws;                             // 32768 B
    uint16_t* dC   = (uint16_t*)((char*)d_ws + 32768);          // 524288 B
    uint16_t* WB   = (uint16_t*)((char*)d_ws + 32768 + 524288); // 73728 B

    prep_kernel<<<272 + NCELL + 128, 256, 0, stream>>>(
        locs, data, density, weight, bias, posT, dC, WB, out);
    conv_kernel<<<BATCH * 128 * 4, 256, 0, stream>>>(posT, dC, WB, out);
}